// Round 6
// baseline (630.556 us; speedup 1.0000x reference)
//
#include <hip/hip_runtime.h>
#include <hip/hip_bf16.h>
#include <cstdint>
#include <cstddef>

// Problem constants
#define NTOK 49
#define DIM 384
#define KDIM 384
#define HEADS 12
#define HD 32
#define BATCH 2048
#define MROWS (BATCH * NTOK)   // 100352 = 784 * 128

typedef unsigned short u16;
typedef __bf16 bf16x8 __attribute__((ext_vector_type(8)));
typedef unsigned short u16x8 __attribute__((ext_vector_type(8)));
typedef float f32x4 __attribute__((ext_vector_type(4)));

__device__ __forceinline__ u16 f2b(float f) {
  union { float f; unsigned u; } v; v.f = f;
  unsigned r = v.u + 0x7fffu + ((v.u >> 16) & 1u);   // RNE bf16
  return (u16)(r >> 16);
}

__device__ __forceinline__ bf16x8 ld_bf8(const u16* p) {
  u16x8 u = *(const u16x8*)p;
  return __builtin_bit_cast(bf16x8, u);
}

__device__ __forceinline__ void gload_lds16(const void* g, void* l) {
  __builtin_amdgcn_global_load_lds(
      (const __attribute__((address_space(1))) unsigned*)g,
      (__attribute__((address_space(3))) unsigned*)l, 16, 0, 0);
}

#define MFMA16(a, b, cacc) __builtin_amdgcn_mfma_f32_16x16x32_bf16(a, b, cacc, 0, 0, 0)

// ---------------- prep: x/w casts + fused bias+mask table, one launch -------
// blocks [0,37632): cast x (9,633,792 float4 quads)
// blocks [37632,38064): cast qkv_w (110,592 quads)
// blocks [38064,38208): cast proj_w (36,864 quads)
// blocks [38208,50496): rpbm table (12288 blocks)
__global__ __launch_bounds__(256) void k_prep(const float* __restrict__ x,
                                              u16* __restrict__ xb,
                                              const float* __restrict__ qkv_w,
                                              u16* __restrict__ wqkvb,
                                              const float* __restrict__ proj_w,
                                              u16* __restrict__ wprojb,
                                              const float* __restrict__ bias_table,
                                              const float* __restrict__ mask,
                                              const int* __restrict__ rel_idx,
                                              float* __restrict__ rpbm) {
  int blk = blockIdx.x;
  if (blk < 38208) {
    const float* in;
    u16* out;
    int i;
    if (blk < 37632) {
      in = x; out = xb; i = blk * 256 + threadIdx.x;
    } else if (blk < 38064) {
      in = qkv_w; out = wqkvb; i = (blk - 37632) * 256 + threadIdx.x;
    } else {
      in = proj_w; out = wprojb; i = (blk - 38064) * 256 + threadIdx.x;
    }
    float4 v = ((const float4*)in)[i];
    ushort4 o;
    o.x = f2b(v.x); o.y = f2b(v.y); o.z = f2b(v.z); o.w = f2b(v.w);
    ((ushort4*)out)[i] = o;
  } else {
    int idx = (blk - 38208) * 256 + threadIdx.x;   // 12*64*4096 entries
    int r  = idx & 3;
    int l  = (idx >> 2) & 63;
    int ni = (idx >> 8) & 3;
    int mi = (idx >> 10) & 3;
    int w  = (idx >> 12) & 63;
    int h  = idx >> 18;
    int row = mi * 16 + (l >> 4) * 4 + r;
    int col = ni * 16 + (l & 15);
    float v = -1e30f;
    if (row < NTOK && col < NTOK)
      v = bias_table[rel_idx[row * NTOK + col] * HEADS + h] +
          mask[(w * NTOK + row) * NTOK + col];
    rpbm[idx] = v;
  }
}

// ---------------- fused qkv GEMM + window attention -------------------------
// One 64-thread block (single wave) per (b, head-triple). grid = 2048*4.
// LDS 14,848 B/block -> ~10-11 blocks/CU (latency hiding), no barriers.
// wv layout (verified in round-4/5 k_fused):
//   q  @ 0      : [64 tok][32 d] stride 80 B
//   k  @ 5120   : [64 tok][32 d] stride 80 B
//   vT @ 10240  : [32 d][64 tok] stride 144 B
//   P  @ 0      : [64 tok][64 j] stride 144 B (overlays q+k after S)
__global__ __launch_bounds__(64) void k_qa(const u16* __restrict__ xb,
                                           const u16* __restrict__ wqkv,
                                           const float* __restrict__ qkv_b,
                                           const float* __restrict__ rpbm,
                                           u16* __restrict__ attnout) {
  __shared__ __attribute__((aligned(16))) char wv[14848];
  int bid = blockIdx.x;
  int t = (bid & 7) * 1024 + (bid >> 3);   // XCD-contiguous (8192 = 8*1024)
  int b = t >> 2, wid = t & 3;
  const int w = b & 63;
  const int lane = threadIdx.x;
  const int c = lane & 15, g = lane >> 4;
  const u16* xbb = xb + (size_t)b * (NTOK * DIM);
  const float scale = 0.17677669529663687f;   // 32^-0.5

  // A-fragment rows (clamped: rows 49..63 duplicate row 48; downstream they
  // are masked in S by rpbm=-1e30 and multiplied by exactly-0 P in PV)
  int arow[4];
#pragma unroll
  for (int mi = 0; mi < 4; ++mi) {
    int row = mi * 16 + c;
    arow[mi] = row < NTOK ? row : NTOK - 1;
  }

#define LOAD_A(af, kt)                                                          \
  _Pragma("unroll") for (int mi = 0; mi < 4; ++mi)                              \
      af[mi] = ld_bf8(xbb + arow[mi] * 384 + (kt) * 32 + g * 8);
#define LOAD_B(bf, kt)                                                          \
  _Pragma("unroll") for (int nj = 0; nj < 6; ++nj)                              \
      bf[nj] = ld_bf8(bp[nj] + (kt) * 32);
#define MFMA_46(af, bf, ACC)                                                    \
  _Pragma("unroll") for (int mi = 0; mi < 4; ++mi)                              \
  _Pragma("unroll") for (int nj = 0; nj < 6; ++nj)                              \
      ACC[mi][nj] = MFMA16(af[mi], bf[nj], ACC[mi][nj]);

  for (int hh = 0; hh < 3; ++hh) {
    const int h = wid * 3 + hh;

    // ---- qkv GEMM for head h: C[64 tok][96] = x[b] @ Wqkv_h^T ----
    int ncol[6];
    ncol[0] = h * 32;        ncol[1] = h * 32 + 16;
    ncol[2] = 384 + h * 32;  ncol[3] = 384 + h * 32 + 16;
    ncol[4] = 768 + h * 32;  ncol[5] = 768 + h * 32 + 16;
    const u16* bp[6];
#pragma unroll
    for (int nj = 0; nj < 6; ++nj)
      bp[nj] = wqkv + (size_t)(ncol[nj] + c) * 384 + g * 8;

    f32x4 acc[4][6] = {};
    {
      bf16x8 afA[4], bfA[6], afB[4], bfB[6];
      LOAD_A(afA, 0); LOAD_B(bfA, 0);
#pragma unroll
      for (int kt = 0; kt < 12; kt += 2) {
        if (kt + 1 < 12) { LOAD_A(afB, kt + 1); LOAD_B(bfB, kt + 1); }
        MFMA_46(afA, bfA, acc);
        if (kt + 2 < 12) { LOAD_A(afA, kt + 2); LOAD_B(bfA, kt + 2); }
        MFMA_46(afB, bfB, acc);
      }
    }

    // WAR guard: previous head's P/vT LDS reads complete before overwrite
    asm volatile("s_waitcnt lgkmcnt(0)" ::: "memory");
    __builtin_amdgcn_sched_barrier(0);

    // ---- bias (+scale for q), scatter to q / k / vT ----
#pragma unroll
    for (int nj = 0; nj < 6; ++nj) {
      float bv = qkv_b[ncol[nj] + c];
      int d = (nj & 1) * 16 + c;
#pragma unroll
      for (int mi = 0; mi < 4; ++mi) {
#pragma unroll
        for (int r = 0; r < 4; ++r) {
          int tok = mi * 16 + g * 4 + r;
          float v = acc[mi][nj][r] + bv;
          if (nj < 2)
            *(u16*)(wv + tok * 80 + d * 2) = f2b(v * scale);        // q
          else if (nj < 4)
            *(u16*)(wv + 5120 + tok * 80 + d * 2) = f2b(v);         // k
          else
            *(u16*)(wv + 10240 + d * 144 + tok * 2) = f2b(v);       // vT
        }
      }
    }
    asm volatile("s_waitcnt lgkmcnt(0)" ::: "memory");
    __builtin_amdgcn_sched_barrier(0);

    // ---- S = q @ k^T (K = 32) ----
    f32x4 s[4][4];
    {
      bf16x8 qf[4], kf[4];
#pragma unroll
      for (int i = 0; i < 4; ++i) {
        qf[i] = ld_bf8((const u16*)(wv + (i * 16 + c) * 80) + g * 8);
        kf[i] = ld_bf8((const u16*)(wv + 5120 + (i * 16 + c) * 80) + g * 8);
      }
      f32x4 zf = {0.f, 0.f, 0.f, 0.f};
#pragma unroll
      for (int mi = 0; mi < 4; ++mi)
#pragma unroll
        for (int nj = 0; nj < 4; ++nj)
          s[mi][nj] = MFMA16(qf[mi], kf[nj], zf);
    }

    // ---- add pre-swizzled bias+mask ----
    const f32x4* rp = (const f32x4*)(rpbm + ((size_t)(h * 64 + w)) * 4096);
#pragma unroll
    for (int mi = 0; mi < 4; ++mi)
#pragma unroll
      for (int nj = 0; nj < 4; ++nj) {
        f32x4 rv = rp[(mi * 4 + nj) * 64 + lane];
#pragma unroll
        for (int r = 0; r < 4; ++r) s[mi][nj][r] += rv[r];
      }

    // ---- row softmax ----
#pragma unroll
    for (int mi = 0; mi < 4; ++mi)
#pragma unroll
      for (int r = 0; r < 4; ++r) {
        float mx = fmaxf(fmaxf(s[mi][0][r], s[mi][1][r]),
                         fmaxf(s[mi][2][r], s[mi][3][r]));
        mx = fmaxf(mx, __shfl_xor(mx, 1));
        mx = fmaxf(mx, __shfl_xor(mx, 2));
        mx = fmaxf(mx, __shfl_xor(mx, 4));
        mx = fmaxf(mx, __shfl_xor(mx, 8));
        float sum = 0.f;
#pragma unroll
        for (int nj = 0; nj < 4; ++nj) {
          float p = __expf(s[mi][nj][r] - mx);
          s[mi][nj][r] = p;
          sum += p;
        }
        sum += __shfl_xor(sum, 1);
        sum += __shfl_xor(sum, 2);
        sum += __shfl_xor(sum, 4);
        sum += __shfl_xor(sum, 8);
        float inv = __builtin_amdgcn_rcpf(sum);
#pragma unroll
        for (int nj = 0; nj < 4; ++nj) s[mi][nj][r] *= inv;
      }

    // ---- P -> LDS bf16 (overlays q,k; stride 144) ----
#pragma unroll
    for (int mi = 0; mi < 4; ++mi)
#pragma unroll
      for (int nj = 0; nj < 4; ++nj) {
        int col = nj * 16 + c;
#pragma unroll
        for (int r = 0; r < 4; ++r) {
          int tok = mi * 16 + g * 4 + r;
          *(u16*)(wv + tok * 144 + col * 2) = f2b(s[mi][nj][r]);
        }
      }
    asm volatile("s_waitcnt lgkmcnt(0)" ::: "memory");
    __builtin_amdgcn_sched_barrier(0);

    // ---- O_h = P @ V (K = 64) ----
    f32x4 o[4][2] = {};
#pragma unroll
    for (int ks = 0; ks < 2; ++ks) {
      bf16x8 vf[2];
#pragma unroll
      for (int n2 = 0; n2 < 2; ++n2)
        vf[n2] = ld_bf8((const u16*)(wv + 10240 + (n2 * 16 + c) * 144) +
                        ks * 32 + g * 8);
#pragma unroll
      for (int mi = 0; mi < 4; ++mi) {
        bf16x8 pa = ld_bf8((const u16*)(wv + (mi * 16 + c) * 144) + ks * 32 + g * 8);
#pragma unroll
        for (int n2 = 0; n2 < 2; ++n2)
          o[mi][n2] = MFMA16(pa, vf[n2], o[mi][n2]);
      }
    }

    // ---- store O[b, tok, h*32 + d] as bf16 ----
    u16* obase = attnout + (size_t)b * (NTOK * DIM) + h * HD;
#pragma unroll
    for (int mi = 0; mi < 4; ++mi)
#pragma unroll
      for (int r = 0; r < 4; ++r) {
        int tok = mi * 16 + g * 4 + r;
        if (tok < NTOK) {
#pragma unroll
          for (int n2 = 0; n2 < 2; ++n2)
            obase[(size_t)tok * DIM + n2 * 16 + c] = f2b(o[mi][n2][r]);
        }
      }
  }
#undef LOAD_A
#undef LOAD_B
#undef MFMA_46
}

// ---------------- NT GEMM, 2-phase double-buffered (proj) -------------------
// C[m,n] = sum_k A[m,k]*B[n,k] + bias[n]; K = 384; f32 out.
template <int NTN, int GD8>
__global__ __launch_bounds__(256) void k_gemm(const u16* __restrict__ A,
                                              const u16* __restrict__ B,
                                              const float* __restrict__ bias,
                                              float* __restrict__ C) {
  __shared__ u16 sh[16384];   // 32KB: 2 x (As 8KB + Bs 8KB); reused by epilogue
  int bid = blockIdx.x;
  int tile = (bid & 7) * GD8 + (bid >> 3);
  int mt = tile / NTN, nt = tile - mt * NTN;
  long m0 = (long)mt * 128;
  int n0 = nt * 128;
  int tid = threadIdx.x;
  int lane = tid & 63, wid = tid >> 6;
  int wr = (wid >> 1) * 64, wc = (wid & 1) * 64;
  int c = lane & 15, g = lane >> 4;

  int srow = wid * 16 + (lane >> 2);
  int scol = (lane & 3) * 8;
  const u16* gA = A + (m0 + srow) * (long)KDIM + scol;
  const u16* gB = B + (long)(n0 + srow) * KDIM + scol;

  f32x4 acc[4][4] = {};

  auto STAGE = [&](int buf, int ktS) {
    u16* As = sh + buf * 8192;
    u16* Bs = As + 4096;
    gload_lds16(gA + ktS, &As[srow * 32 + scol]);
    gload_lds16(gA + ktS + 64L * KDIM, &As[(srow + 64) * 32 + scol]);
    gload_lds16(gB + ktS, &Bs[srow * 32 + scol]);
    gload_lds16(gB + ktS + 64L * KDIM, &Bs[(srow + 64) * 32 + scol]);
  };

  STAGE(0, 0);
  __syncthreads();
  int cur = 0;
  for (int kt = 0; kt < KDIM; kt += 32) {
    if (kt + 32 < KDIM) STAGE(cur ^ 1, kt + 32);
    const u16* As = sh + cur * 8192;
    const u16* Bs = As + 4096;
    bf16x8 af[4], bfr[4];
#pragma unroll
    for (int i = 0; i < 4; ++i) {
      af[i]  = ld_bf8(&As[(wr + i * 16 + c) * 32 + g * 8]);
      bfr[i] = ld_bf8(&Bs[(wc + i * 16 + c) * 32 + g * 8]);
    }
#pragma unroll
    for (int mi = 0; mi < 4; ++mi)
#pragma unroll
      for (int ni = 0; ni < 4; ++ni)
        acc[mi][ni] = __builtin_amdgcn_mfma_f32_16x16x32_bf16(
            af[mi], bfr[ni], acc[mi][ni], 0, 0, 0);
    __syncthreads();
    cur ^= 1;
  }

  float* shf = (float*)sh;   // 64 rows x 128 cols f32
#pragma unroll
  for (int chunk = 0; chunk < 2; ++chunk) {
    __syncthreads();
    if ((wr >> 6) == chunk) {
#pragma unroll
      for (int mi = 0; mi < 4; ++mi)
#pragma unroll
        for (int ni = 0; ni < 4; ++ni) {
          int col = wc + ni * 16 + c;
          float bv = bias[n0 + col];
#pragma unroll
          for (int r = 0; r < 4; ++r) {
            int lrow = mi * 16 + g * 4 + r;
            shf[lrow * 128 + col] = acc[mi][ni][r] + bv;
          }
        }
    }
    __syncthreads();
#pragma unroll
    for (int rep = 0; rep < 8; ++rep) {
      int idx = rep * 1024 + tid * 4;
      int row = idx >> 7, col = idx & 127;
      *(float4*)(C + (m0 + chunk * 64 + row) * 384 + n0 + col) =
          *(const float4*)&shf[idx];
    }
  }
}

// ---------------------------------------------------------------------------
extern "C" void kernel_launch(void* const* d_in, const int* in_sizes, int n_in,
                              void* d_out, int out_size, void* d_ws, size_t ws_size,
                              hipStream_t stream) {
  const float* x       = (const float*)d_in[0];
  const float* qkv_w   = (const float*)d_in[1];
  const float* qkv_b   = (const float*)d_in[2];
  const float* proj_w  = (const float*)d_in[3];
  const float* proj_b  = (const float*)d_in[4];
  const float* bias_tb = (const float*)d_in[5];
  const float* mask    = (const float*)d_in[6];
  const int*   rel_idx = (const int*)d_in[7];
  float* out = (float*)d_out;

  char* ws = (char*)d_ws;
  u16*   xb      = (u16*)(ws + 0);              //  77,070,336  x bf16
  u16*   wqkvb   = (u16*)(ws + 77070336);       //     884,736  qkv_w bf16
  u16*   wprojb  = (u16*)(ws + 77955072);       //     294,912  proj_w bf16
  float* rpbm    = (float*)(ws + 78249984);     //  12,582,912  bias+mask
  u16*   attnout = (u16*)(ws + 90832896);       //  77,070,336  attn out bf16
  // total 167,903,232 B

  // 1) prep: casts + fused bias+mask table
  k_prep<<<50496, 256, 0, stream>>>(x, xb, qkv_w, wqkvb, proj_w, wprojb,
                                    bias_tb, mask, rel_idx, rpbm);

  // 2) fused qkv + attention: one wave per (b, 3 heads)
  k_qa<<<8192, 64, 0, stream>>>(xb, wqkvb, qkv_b, rpbm, attnout);

  // 3) proj GEMM: [100352,384] x [384,384]^T + bias -> f32 d_out
  k_gemm<3, 294><<<2352, 256, 0, stream>>>(attnout, wprojb, proj_b, out);

  (void)in_sizes; (void)n_in; (void)out_size; (void)ws_size;
}

// Round 7
// 371.944 us; speedup vs baseline: 1.6953x; 1.6953x over previous
//
#include <hip/hip_runtime.h>
#include <hip/hip_bf16.h>
#include <cstdint>
#include <cstddef>

// Problem constants
#define NTOK 49
#define DIM 384
#define KDIM 384
#define HEADS 12
#define HD 32
#define BATCH 2048
#define MROWS (BATCH * NTOK)   // 100352 = 784 * 128

typedef unsigned short u16;
typedef __bf16 bf16x8 __attribute__((ext_vector_type(8)));
typedef unsigned short u16x8 __attribute__((ext_vector_type(8)));
typedef float f32x4 __attribute__((ext_vector_type(4)));

__device__ __forceinline__ u16 f2b(float f) {
  union { float f; unsigned u; } v; v.f = f;
  unsigned r = v.u + 0x7fffu + ((v.u >> 16) & 1u);   // RNE bf16
  return (u16)(r >> 16);
}

__device__ __forceinline__ bf16x8 ld_bf8(const u16* p) {
  u16x8 u = *(const u16x8*)p;
  return __builtin_bit_cast(bf16x8, u);
}

__device__ __forceinline__ void gload_lds16(const void* g, void* l) {
  __builtin_amdgcn_global_load_lds(
      (const __attribute__((address_space(1))) unsigned*)g,
      (__attribute__((address_space(3))) unsigned*)l, 16, 0, 0);
}

// ---------------- prep: x/w casts + fused bias+mask table, one launch -------
__global__ __launch_bounds__(256) void k_prep(const float* __restrict__ x,
                                              u16* __restrict__ xb,
                                              const float* __restrict__ qkv_w,
                                              u16* __restrict__ wqkvb,
                                              const float* __restrict__ proj_w,
                                              u16* __restrict__ wprojb,
                                              const float* __restrict__ bias_table,
                                              const float* __restrict__ mask,
                                              const int* __restrict__ rel_idx,
                                              float* __restrict__ rpbm) {
  int blk = blockIdx.x;
  if (blk < 38208) {
    const float* in;
    u16* out;
    int i;
    if (blk < 37632) {
      in = x; out = xb; i = blk * 256 + threadIdx.x;
    } else if (blk < 38064) {
      in = qkv_w; out = wqkvb; i = (blk - 37632) * 256 + threadIdx.x;
    } else {
      in = proj_w; out = wprojb; i = (blk - 38064) * 256 + threadIdx.x;
    }
    float4 v = ((const float4*)in)[i];
    ushort4 o;
    o.x = f2b(v.x); o.y = f2b(v.y); o.z = f2b(v.z); o.w = f2b(v.w);
    ((ushort4*)out)[i] = o;
  } else {
    int idx = (blk - 38208) * 256 + threadIdx.x;   // 12*64*4096 entries
    int r  = idx & 3;
    int l  = (idx >> 2) & 63;
    int ni = (idx >> 8) & 3;
    int mi = (idx >> 10) & 3;
    int w  = (idx >> 12) & 63;
    int h  = idx >> 18;
    int row = mi * 16 + (l >> 4) * 4 + r;
    int col = ni * 16 + (l & 15);
    float v = -1e30f;
    if (row < NTOK && col < NTOK)
      v = bias_table[rel_idx[row * NTOK + col] * HEADS + h] +
          mask[(w * NTOK + row) * NTOK + col];
    rpbm[idx] = v;
  }
}

// ------- NT GEMM, 3-buffer rotation with counted vmcnt (T3/T4 minimum) -----
// C[m,n] = sum_k A[m,k]*B[n,k] + bias[n]; K = 384 (12 tiles of 32).
// Per iter: wait vmcnt(8) [tile t ready, 8 newer loads in flight], barrier,
// ds_read frags, lgkmcnt(0)+barrier [WAR-safe], restage buf t%3 for t+3, MFMA.
template <int OUT_BF16, int NCOLS, int NTN, int GD8>
__global__ __launch_bounds__(256) void k_gemm(const u16* __restrict__ A,
                                              const u16* __restrict__ B,
                                              const float* __restrict__ bias,
                                              void* __restrict__ Cv) {
  __shared__ u16 sh[24576];   // 48KB: 3 x (As 8KB + Bs 8KB); reused by epilogue
  int bid = blockIdx.x;
  int tile = (bid & 7) * GD8 + (bid >> 3);   // XCD-contiguous (grid % 8 == 0)
  int mt = tile / NTN, nt = tile - mt * NTN;
  long m0 = (long)mt * 128;
  int n0 = nt * 128;
  int tid = threadIdx.x;
  int lane = tid & 63, wid = tid >> 6;
  int wr = (wid >> 1) * 64, wc = (wid & 1) * 64;
  int c = lane & 15, g = lane >> 4;

  // gload_lds staging coords: LDS byte offset = wid*1024 + lane*16 ->
  // wave-uniform base + lane*16 (required layout for global_load_lds)
  int srow = wid * 16 + (lane >> 2);
  int scol = (lane & 3) * 8;
  const u16* gA = A + (m0 + srow) * (long)KDIM + scol;
  const u16* gB = B + (long)(n0 + srow) * KDIM + scol;

  f32x4 acc[4][4] = {};

#define STAGE(BUF, KT)                                                         \
  {                                                                            \
    u16* As_ = sh + (BUF) * 8192;                                              \
    u16* Bs_ = As_ + 4096;                                                     \
    gload_lds16(gA + (KT), &As_[srow * 32 + scol]);                            \
    gload_lds16(gA + (KT) + 64L * KDIM, &As_[(srow + 64) * 32 + scol]);        \
    gload_lds16(gB + (KT), &Bs_[srow * 32 + scol]);                            \
    gload_lds16(gB + (KT) + 64L * KDIM, &Bs_[(srow + 64) * 32 + scol]);        \
  }

#define GITER(T, NV)                                                           \
  {                                                                            \
    asm volatile("s_waitcnt vmcnt(" #NV ")" ::: "memory");                     \
    __builtin_amdgcn_s_barrier();                                              \
    const u16* As = sh + ((T) % 3) * 8192;                                     \
    const u16* Bs = As + 4096;                                                 \
    bf16x8 af[4], bfr[4];                                                      \
    _Pragma("unroll") for (int i = 0; i < 4; ++i) {                            \
      af[i]  = ld_bf8(&As[(wr + i * 16 + c) * 32 + g * 8]);                    \
      bfr[i] = ld_bf8(&Bs[(wc + i * 16 + c) * 32 + g * 8]);                    \
    }                                                                          \
    asm volatile("s_waitcnt lgkmcnt(0)" ::: "memory");                         \
    __builtin_amdgcn_s_barrier();                                              \
    if ((T) + 3 < 12) STAGE((T) % 3, ((T) + 3) * 32);                          \
    _Pragma("unroll") for (int mi = 0; mi < 4; ++mi)                           \
    _Pragma("unroll") for (int ni = 0; ni < 4; ++ni)                           \
        acc[mi][ni] = __builtin_amdgcn_mfma_f32_16x16x32_bf16(                 \
            af[mi], bfr[ni], acc[mi][ni], 0, 0, 0);                            \
  }

  STAGE(0, 0);
  STAGE(1, 32);
  STAGE(2, 64);
  GITER(0, 8)  GITER(1, 8)  GITER(2, 8)  GITER(3, 8)
  GITER(4, 8)  GITER(5, 8)  GITER(6, 8)  GITER(7, 8)
  GITER(8, 8)  GITER(9, 8)  GITER(10, 4) GITER(11, 0)
#undef GITER
#undef STAGE

  // ---- epilogue: LDS transit -> coalesced 16B stores ----
  if (OUT_BF16) {
    u16* C = (u16*)Cv;
#pragma unroll
    for (int mi = 0; mi < 4; ++mi)
#pragma unroll
      for (int ni = 0; ni < 4; ++ni) {
        int col = wc + ni * 16 + c;
        float bv = bias[n0 + col];
#pragma unroll
        for (int r = 0; r < 4; ++r) {
          int row = wr + mi * 16 + g * 4 + r;
          sh[row * 128 + col] = f2b(acc[mi][ni][r] + bv);
        }
      }
    __syncthreads();
#pragma unroll
    for (int rep = 0; rep < 8; ++rep) {
      int idx = rep * 2048 + tid * 8;      // u16 units; 16 rows per rep
      int row = idx >> 7, col = idx & 127;
      *(u16x8*)(C + (m0 + row) * NCOLS + n0 + col) = *(const u16x8*)&sh[idx];
    }
  } else {
    float* C = (float*)Cv;
    float* shf = (float*)sh;               // 64 rows x 128 cols f32 = 32KB
#pragma unroll
    for (int chunk = 0; chunk < 2; ++chunk) {
      __syncthreads();
      if ((wr >> 6) == chunk) {
#pragma unroll
        for (int mi = 0; mi < 4; ++mi)
#pragma unroll
          for (int ni = 0; ni < 4; ++ni) {
            int col = wc + ni * 16 + c;
            float bv = bias[n0 + col];
#pragma unroll
            for (int r = 0; r < 4; ++r) {
              int lrow = mi * 16 + g * 4 + r;
              shf[lrow * 128 + col] = acc[mi][ni][r] + bv;
            }
          }
      }
      __syncthreads();
#pragma unroll
      for (int rep = 0; rep < 8; ++rep) {
        int idx = rep * 1024 + tid * 4;    // f32 units; 8 rows per rep
        int row = idx >> 7, col = idx & 127;
        *(float4*)(C + (m0 + chunk * 64 + row) * NCOLS + n0 + col) =
            *(const float4*)&shf[idx];
      }
    }
  }
}

// ---------------- fused window attention: one wave per (b, h) ----------------
__global__ __launch_bounds__(256) void k_attn(const u16* __restrict__ qkv,
                                              const float* __restrict__ rpbm,
                                              u16* __restrict__ attnout) {
  __shared__ u16 P_lds[4][64 * 64];
  __shared__ u16 vT_lds[4][32 * 64];
  int lane = threadIdx.x & 63, wid = threadIdx.x >> 6;
  // w-major remap: 96 consecutive blocks share one window's rpbm tables (L2)
  int blk = blockIdx.x;                  // 0..6143
  int w = blk / 96;
  int rr = blk - w * 96;
  int j = rr / 3;
  int hb = rr - j * 3;
  int b = j * 64 + w;
  int h = hb * 4 + wid;
  const u16* base = qkv + (size_t)b * (NTOK * 1152);
  int c = lane & 15, g = lane >> 4;

  // ---- stage V transposed into LDS: vT[d][j], swizzled byte ^= (d&7)<<4 ----
  u16* vt = vT_lds[wid];
  {
    const u16* vbase = base + 2 * DIM + h * HD;
#pragma unroll
    for (int t = 0; t < 4; ++t) {
      int idx = t * 64 + lane;
      int jj = idx >> 2, d0 = (idx & 3) * 8;
      int jr = jj < NTOK ? jj : NTOK - 1;
      u16x8 vv = *(const u16x8*)(vbase + (size_t)jr * 1152 + d0);
#pragma unroll
      for (int dd = 0; dd < 8; ++dd) {
        int d = d0 + dd;
        int byte = (d * 128 + jj * 2) ^ ((d & 7) << 4);
        *(u16*)((char*)vt + byte) = (u16)vv[dd];
      }
    }
  }

  // ---- Q/K fragments straight from global (fragment-order along K=32) ----
  bf16x8 qa[4], kb[4];
#pragma unroll
  for (int mi = 0; mi < 4; ++mi) {
    int row = mi * 16 + c; if (row > NTOK - 1) row = NTOK - 1;
    qa[mi] = ld_bf8(base + (size_t)row * 1152 + h * HD + g * 8);
  }
#pragma unroll
  for (int ni = 0; ni < 4; ++ni) {
    int row = ni * 16 + c; if (row > NTOK - 1) row = NTOK - 1;
    kb[ni] = ld_bf8(base + (size_t)row * 1152 + DIM + h * HD + g * 8);
  }

  // ---- S = q @ k^T ----
  f32x4 s[4][4] = {};
#pragma unroll
  for (int mi = 0; mi < 4; ++mi)
#pragma unroll
    for (int ni = 0; ni < 4; ++ni)
      s[mi][ni] = __builtin_amdgcn_mfma_f32_16x16x32_bf16(qa[mi], kb[ni],
                                                          s[mi][ni], 0, 0, 0);

  // ---- scale + (bias+mask) from pre-swizzled table ----
  const float scale = 0.17677669529663687f;   // 32^-0.5
  const f32x4* rp = (const f32x4*)(rpbm + ((size_t)(h * 64 + w)) * 4096);
#pragma unroll
  for (int mi = 0; mi < 4; ++mi)
#pragma unroll
    for (int ni = 0; ni < 4; ++ni) {
      f32x4 rv = rp[(mi * 4 + ni) * 64 + lane];
#pragma unroll
      for (int r = 0; r < 4; ++r)
        s[mi][ni][r] = s[mi][ni][r] * scale + rv[r];
    }

  // ---- row softmax: row lives in one 16-lane group (per mi, r) ----
#pragma unroll
  for (int mi = 0; mi < 4; ++mi)
#pragma unroll
    for (int r = 0; r < 4; ++r) {
      float mx = fmaxf(fmaxf(s[mi][0][r], s[mi][1][r]),
                       fmaxf(s[mi][2][r], s[mi][3][r]));
      mx = fmaxf(mx, __shfl_xor(mx, 1));
      mx = fmaxf(mx, __shfl_xor(mx, 2));
      mx = fmaxf(mx, __shfl_xor(mx, 4));
      mx = fmaxf(mx, __shfl_xor(mx, 8));
      float sum = 0.f;
#pragma unroll
      for (int ni = 0; ni < 4; ++ni) {
        float p = __expf(s[mi][ni][r] - mx);
        s[mi][ni][r] = p;
        sum += p;
      }
      sum += __shfl_xor(sum, 1);
      sum += __shfl_xor(sum, 2);
      sum += __shfl_xor(sum, 4);
      sum += __shfl_xor(sum, 8);
      float inv = __builtin_amdgcn_rcpf(sum);
#pragma unroll
      for (int ni = 0; ni < 4; ++ni) s[mi][ni][r] *= inv;
    }

  // ---- P -> LDS as bf16 (swizzled) ----
  u16* pl = P_lds[wid];
#pragma unroll
  for (int mi = 0; mi < 4; ++mi)
#pragma unroll
    for (int ni = 0; ni < 4; ++ni) {
      int col = ni * 16 + c;
#pragma unroll
      for (int r = 0; r < 4; ++r) {
        int row = mi * 16 + g * 4 + r;
        int byte = (row * 128 + col * 2) ^ ((row & 7) << 4);
        *(u16*)((char*)pl + byte) = f2b(s[mi][ni][r]);
      }
    }
  asm volatile("s_waitcnt lgkmcnt(0)" ::: "memory");  // wave's LDS writes visible

  // ---- O = P @ V ----
  f32x4 o[4][2] = {};
#pragma unroll
  for (int ks = 0; ks < 2; ++ks) {
    bf16x8 vb[2];
#pragma unroll
    for (int n2 = 0; n2 < 2; ++n2) {
      int d = n2 * 16 + c;
      int byte = (d * 128 + ks * 64 + g * 16) ^ ((d & 7) << 4);
      vb[n2] = __builtin_bit_cast(bf16x8, *(const u16x8*)((const char*)vt + byte));
    }
#pragma unroll
    for (int mi = 0; mi < 4; ++mi) {
      int row = mi * 16 + c;
      int byte = (row * 128 + ks * 64 + g * 16) ^ ((row & 7) << 4);
      bf16x8 pa = __builtin_bit_cast(bf16x8, *(const u16x8*)((const char*)pl + byte));
#pragma unroll
      for (int n2 = 0; n2 < 2; ++n2)
        o[mi][n2] = __builtin_amdgcn_mfma_f32_16x16x32_bf16(pa, vb[n2],
                                                            o[mi][n2], 0, 0, 0);
    }
  }

  // ---- store O[b, row, h*32 + d] as bf16 ----
  u16* obase = attnout + (size_t)b * (NTOK * DIM) + h * HD;
#pragma unroll
  for (int mi = 0; mi < 4; ++mi)
#pragma unroll
    for (int r = 0; r < 4; ++r) {
      int row = mi * 16 + g * 4 + r;
      if (row < NTOK) {
#pragma unroll
        for (int n2 = 0; n2 < 2; ++n2)
          obase[(size_t)row * DIM + n2 * 16 + c] = f2b(o[mi][n2][r]);
      }
    }
}

// ---------------------------------------------------------------------------
extern "C" void kernel_launch(void* const* d_in, const int* in_sizes, int n_in,
                              void* d_out, int out_size, void* d_ws, size_t ws_size,
                              hipStream_t stream) {
  const float* x       = (const float*)d_in[0];
  const float* qkv_w   = (const float*)d_in[1];
  const float* qkv_b   = (const float*)d_in[2];
  const float* proj_w  = (const float*)d_in[3];
  const float* proj_b  = (const float*)d_in[4];
  const float* bias_tb = (const float*)d_in[5];
  const float* mask    = (const float*)d_in[6];
  const int*   rel_idx = (const int*)d_in[7];
  float* out = (float*)d_out;

  char* ws = (char*)d_ws;
  u16*   xb      = (u16*)(ws + 0);                  //  77,070,336  x bf16
  u16*   wqkvb   = (u16*)(ws + 77070336);           //     884,736  qkv_w bf16
  u16*   wprojb  = (u16*)(ws + 77955072);           //     294,912  proj_w bf16
  float* rpbm    = (float*)(ws + 78249984);         //  12,582,912  bias+mask
  u16*   qkv     = (u16*)(ws + 90832896);           // 231,211,008  qkv bf16
  u16*   attnout = (u16*)(ws + 322043904);          //  77,070,336  attn out bf16
  // total = 399,114,240 bytes

  // 1) prep: all casts + fused bias+mask table
  k_prep<<<50496, 256, 0, stream>>>(x, xb, qkv_w, wqkvb, proj_w, wprojb,
                                    bias_tb, mask, rel_idx, rpbm);

  // 2) QKV GEMM: [100352,384] x [1152,384]^T -> bf16 [100352,1152]
  k_gemm<1, 1152, 9, 882><<<7056, 256, 0, stream>>>(xb, wqkvb, qkv_b, (void*)qkv);

  // 3) window attention -> bf16 [100352,384]
  k_attn<<<6144, 256, 0, stream>>>(qkv, rpbm, attnout);

  // 4) proj GEMM: [100352,384] x [384,384]^T + bias -> f32 d_out
  k_gemm<0, 384, 3, 294><<<2352, 256, 0, stream>>>(attnout, wprojb, proj_b,
                                                   (void*)out);

  (void)in_sizes; (void)n_in; (void)out_size; (void)ws_size;
}

// Round 8
// 350.315 us; speedup vs baseline: 1.8000x; 1.0617x over previous
//
#include <hip/hip_runtime.h>
#include <hip/hip_bf16.h>
#include <cstdint>
#include <cstddef>

// Problem constants
#define NTOK 49
#define DIM 384
#define KDIM 384
#define HEADS 12
#define HD 32
#define BATCH 2048
#define MROWS (BATCH * NTOK)   // 100352 = 784 * 128

typedef unsigned short u16;
typedef __bf16 bf16x8 __attribute__((ext_vector_type(8)));
typedef unsigned short u16x8 __attribute__((ext_vector_type(8)));
typedef float f32x4 __attribute__((ext_vector_type(4)));

__device__ __forceinline__ u16 f2b(float f) {
  union { float f; unsigned u; } v; v.f = f;
  unsigned r = v.u + 0x7fffu + ((v.u >> 16) & 1u);   // RNE bf16
  return (u16)(r >> 16);
}

__device__ __forceinline__ bf16x8 ld_bf8(const u16* p) {
  u16x8 u = *(const u16x8*)p;
  return __builtin_bit_cast(bf16x8, u);
}

__device__ __forceinline__ void gload_lds16(const void* g, void* l) {
  __builtin_amdgcn_global_load_lds(
      (const __attribute__((address_space(1))) unsigned*)g,
      (__attribute__((address_space(3))) unsigned*)l, 16, 0, 0);
}

// ---------------- prep: x/w casts + fused bias+mask table, one launch -------
__global__ __launch_bounds__(256) void k_prep(const float* __restrict__ x,
                                              u16* __restrict__ xb,
                                              const float* __restrict__ qkv_w,
                                              u16* __restrict__ wqkvb,
                                              const float* __restrict__ proj_w,
                                              u16* __restrict__ wprojb,
                                              const float* __restrict__ bias_table,
                                              const float* __restrict__ mask,
                                              const int* __restrict__ rel_idx,
                                              float* __restrict__ rpbm) {
  int blk = blockIdx.x;
  if (blk < 38208) {
    const float* in;
    u16* out;
    int i;
    if (blk < 37632) {
      in = x; out = xb; i = blk * 256 + threadIdx.x;
    } else if (blk < 38064) {
      in = qkv_w; out = wqkvb; i = (blk - 37632) * 256 + threadIdx.x;
    } else {
      in = proj_w; out = wprojb; i = (blk - 38064) * 256 + threadIdx.x;
    }
    float4 v = ((const float4*)in)[i];
    ushort4 o;
    o.x = f2b(v.x); o.y = f2b(v.y); o.z = f2b(v.z); o.w = f2b(v.w);
    ((ushort4*)out)[i] = o;
  } else {
    int idx = (blk - 38208) * 256 + threadIdx.x;   // 12*64*4096 entries
    int r  = idx & 3;
    int l  = (idx >> 2) & 63;
    int ni = (idx >> 8) & 3;
    int mi = (idx >> 10) & 3;
    int w  = (idx >> 12) & 63;
    int h  = idx >> 18;
    int row = mi * 16 + (l >> 4) * 4 + r;
    int col = ni * 16 + (l & 15);
    float v = -1e30f;
    if (row < NTOK && col < NTOK)
      v = bias_table[rel_idx[row * NTOK + col] * HEADS + h] +
          mask[(w * NTOK + row) * NTOK + col];
    rpbm[idx] = v;
  }
}

// ------- NT GEMM, 3-buffer counted-vmcnt rotation + T2 LDS swizzle ---------
// C[m,n] = sum_k A[m,k]*B[n,k] + bias[n]; K = 384 (12 tiles of 32).
// LDS swizzle (involution, bits 4-5 ^= row bits 1-2):
//   physical_byte = logical_byte ^ (((byte>>7)&3)<<4)
// Write side: gload_lds dest stays LINEAR; the per-lane GLOBAL source is
// pre-swizzled: seg = (lane&3) ^ ((lane>>3)&3)   (rule #21: source + read
// use the same involution, dest linear).
// Read side: segment index g ^ ((c>>1)&3). 16-lane row-groups then cover all
// 32 banks with 2-way aliasing (free, m136) instead of 8-way.
template <int OUT_BF16, int NCOLS, int NTN, int GD8>
__global__ __launch_bounds__(256) void k_gemm(const u16* __restrict__ A,
                                              const u16* __restrict__ B,
                                              const float* __restrict__ bias,
                                              void* __restrict__ Cv) {
  __shared__ u16 sh[24576];   // 48KB: 3 x (As 8KB + Bs 8KB); reused by epilogue
  int bid = blockIdx.x;
  int tile = (bid & 7) * GD8 + (bid >> 3);   // XCD-contiguous (grid % 8 == 0)
  int mt = tile / NTN, nt = tile - mt * NTN;
  long m0 = (long)mt * 128;
  int n0 = nt * 128;
  int tid = threadIdx.x;
  int lane = tid & 63, wid = tid >> 6;
  int wr = (wid >> 1) * 64, wc = (wid & 1) * 64;
  int c = lane & 15, g = lane >> 4;
  int gsw = (g ^ ((c >> 1) & 3)) * 8;        // swizzled read segment (u16 units)

  // staging coords: LDS dest linear (wid*1024 + lane*16 bytes); global source
  // column segment pre-swizzled so data lands at its swizzled physical slot
  int srow = wid * 16 + (lane >> 2);
  int scol = ((lane & 3) ^ ((lane >> 3) & 3)) * 8;
  const u16* gA = A + (m0 + srow) * (long)KDIM + scol;
  const u16* gB = B + (long)(n0 + srow) * KDIM + scol;
  // LDS write offsets remain the LINEAR lane slots (srow, lane&3):
  int lrow = srow, lseg = (lane & 3) * 8;

  f32x4 acc[4][4] = {};

#define STAGE(BUF, KT)                                                         \
  {                                                                            \
    u16* As_ = sh + (BUF) * 8192;                                              \
    u16* Bs_ = As_ + 4096;                                                     \
    gload_lds16(gA + (KT), &As_[lrow * 32 + lseg]);                            \
    gload_lds16(gA + (KT) + 64L * KDIM, &As_[(lrow + 64) * 32 + lseg]);        \
    gload_lds16(gB + (KT), &Bs_[lrow * 32 + lseg]);                            \
    gload_lds16(gB + (KT) + 64L * KDIM, &Bs_[(lrow + 64) * 32 + lseg]);        \
  }

#define GITER(T, NV)                                                           \
  {                                                                            \
    asm volatile("s_waitcnt vmcnt(" #NV ")" ::: "memory");                     \
    __builtin_amdgcn_s_barrier();                                              \
    const u16* As = sh + ((T) % 3) * 8192;                                     \
    const u16* Bs = As + 4096;                                                 \
    bf16x8 af[4], bfr[4];                                                      \
    _Pragma("unroll") for (int i = 0; i < 4; ++i) {                            \
      af[i]  = ld_bf8(&As[(wr + i * 16 + c) * 32 + gsw]);                      \
      bfr[i] = ld_bf8(&Bs[(wc + i * 16 + c) * 32 + gsw]);                      \
    }                                                                          \
    asm volatile("s_waitcnt lgkmcnt(0)" ::: "memory");                         \
    __builtin_amdgcn_s_barrier();                                              \
    if ((T) + 3 < 12) STAGE((T) % 3, ((T) + 3) * 32);                          \
    __builtin_amdgcn_s_setprio(1);                                             \
    _Pragma("unroll") for (int mi = 0; mi < 4; ++mi)                           \
    _Pragma("unroll") for (int ni = 0; ni < 4; ++ni)                           \
        acc[mi][ni] = __builtin_amdgcn_mfma_f32_16x16x32_bf16(                 \
            af[mi], bfr[ni], acc[mi][ni], 0, 0, 0);                            \
    __builtin_amdgcn_s_setprio(0);                                             \
  }

  STAGE(0, 0);
  STAGE(1, 32);
  STAGE(2, 64);
  GITER(0, 8)  GITER(1, 8)  GITER(2, 8)  GITER(3, 8)
  GITER(4, 8)  GITER(5, 8)  GITER(6, 8)  GITER(7, 8)
  GITER(8, 8)  GITER(9, 8)  GITER(10, 4) GITER(11, 0)
#undef GITER
#undef STAGE

  // ---- epilogue: LDS transit -> coalesced 16B stores ----
  if (OUT_BF16) {
    u16* C = (u16*)Cv;
#pragma unroll
    for (int mi = 0; mi < 4; ++mi)
#pragma unroll
      for (int ni = 0; ni < 4; ++ni) {
        int col = wc + ni * 16 + c;
        float bv = bias[n0 + col];
#pragma unroll
        for (int r = 0; r < 4; ++r) {
          int row = wr + mi * 16 + g * 4 + r;
          sh[row * 128 + col] = f2b(acc[mi][ni][r] + bv);
        }
      }
    __syncthreads();
#pragma unroll
    for (int rep = 0; rep < 8; ++rep) {
      int idx = rep * 2048 + tid * 8;      // u16 units; 16 rows per rep
      int row = idx >> 7, col = idx & 127;
      *(u16x8*)(C + (m0 + row) * NCOLS + n0 + col) = *(const u16x8*)&sh[idx];
    }
  } else {
    float* C = (float*)Cv;
    float* shf = (float*)sh;               // 64 rows x 128 cols f32 = 32KB
#pragma unroll
    for (int chunk = 0; chunk < 2; ++chunk) {
      __syncthreads();
      if ((wr >> 6) == chunk) {
#pragma unroll
        for (int mi = 0; mi < 4; ++mi)
#pragma unroll
          for (int ni = 0; ni < 4; ++ni) {
            int col = wc + ni * 16 + c;
            float bv = bias[n0 + col];
#pragma unroll
            for (int r = 0; r < 4; ++r) {
              int lr = mi * 16 + g * 4 + r;
              shf[lr * 128 + col] = acc[mi][ni][r] + bv;
            }
          }
      }
      __syncthreads();
#pragma unroll
      for (int rep = 0; rep < 8; ++rep) {
        int idx = rep * 1024 + tid * 4;    // f32 units; 8 rows per rep
        int row = idx >> 7, col = idx & 127;
        *(float4*)(C + (m0 + chunk * 64 + row) * NCOLS + n0 + col) =
            *(const float4*)&shf[idx];
      }
    }
  }
}

// ---------------- fused window attention: one wave per (b, h) ----------------
__global__ __launch_bounds__(256) void k_attn(const u16* __restrict__ qkv,
                                              const float* __restrict__ rpbm,
                                              u16* __restrict__ attnout) {
  __shared__ u16 P_lds[4][64 * 64];
  __shared__ u16 vT_lds[4][32 * 64];
  int lane = threadIdx.x & 63, wid = threadIdx.x >> 6;
  // w-major remap: 96 consecutive blocks share one window's rpbm tables (L2)
  int blk = blockIdx.x;                  // 0..6143
  int w = blk / 96;
  int rr = blk - w * 96;
  int j = rr / 3;
  int hb = rr - j * 3;
  int b = j * 64 + w;
  int h = hb * 4 + wid;
  const u16* base = qkv + (size_t)b * (NTOK * 1152);
  int c = lane & 15, g = lane >> 4;

  // ---- stage V transposed into LDS: vT[d][j], swizzled byte ^= (d&7)<<4 ----
  u16* vt = vT_lds[wid];
  {
    const u16* vbase = base + 2 * DIM + h * HD;
#pragma unroll
    for (int t = 0; t < 4; ++t) {
      int idx = t * 64 + lane;
      int jj = idx >> 2, d0 = (idx & 3) * 8;
      int jr = jj < NTOK ? jj : NTOK - 1;
      u16x8 vv = *(const u16x8*)(vbase + (size_t)jr * 1152 + d0);
#pragma unroll
      for (int dd = 0; dd < 8; ++dd) {
        int d = d0 + dd;
        int byte = (d * 128 + jj * 2) ^ ((d & 7) << 4);
        *(u16*)((char*)vt + byte) = (u16)vv[dd];
      }
    }
  }

  // ---- Q/K fragments straight from global (fragment-order along K=32) ----
  bf16x8 qa[4], kb[4];
#pragma unroll
  for (int mi = 0; mi < 4; ++mi) {
    int row = mi * 16 + c; if (row > NTOK - 1) row = NTOK - 1;
    qa[mi] = ld_bf8(base + (size_t)row * 1152 + h * HD + g * 8);
  }
#pragma unroll
  for (int ni = 0; ni < 4; ++ni) {
    int row = ni * 16 + c; if (row > NTOK - 1) row = NTOK - 1;
    kb[ni] = ld_bf8(base + (size_t)row * 1152 + DIM + h * HD + g * 8);
  }

  // ---- S = q @ k^T ----
  f32x4 s[4][4] = {};
#pragma unroll
  for (int mi = 0; mi < 4; ++mi)
#pragma unroll
    for (int ni = 0; ni < 4; ++ni)
      s[mi][ni] = __builtin_amdgcn_mfma_f32_16x16x32_bf16(qa[mi], kb[ni],
                                                          s[mi][ni], 0, 0, 0);

  // ---- scale + (bias+mask) from pre-swizzled table ----
  const float scale = 0.17677669529663687f;   // 32^-0.5
  const f32x4* rp = (const f32x4*)(rpbm + ((size_t)(h * 64 + w)) * 4096);
#pragma unroll
  for (int mi = 0; mi < 4; ++mi)
#pragma unroll
    for (int ni = 0; ni < 4; ++ni) {
      f32x4 rv = rp[(mi * 4 + ni) * 64 + lane];
#pragma unroll
      for (int r = 0; r < 4; ++r)
        s[mi][ni][r] = s[mi][ni][r] * scale + rv[r];
    }

  // ---- row softmax: row lives in one 16-lane group (per mi, r) ----
#pragma unroll
  for (int mi = 0; mi < 4; ++mi)
#pragma unroll
    for (int r = 0; r < 4; ++r) {
      float mx = fmaxf(fmaxf(s[mi][0][r], s[mi][1][r]),
                       fmaxf(s[mi][2][r], s[mi][3][r]));
      mx = fmaxf(mx, __shfl_xor(mx, 1));
      mx = fmaxf(mx, __shfl_xor(mx, 2));
      mx = fmaxf(mx, __shfl_xor(mx, 4));
      mx = fmaxf(mx, __shfl_xor(mx, 8));
      float sum = 0.f;
#pragma unroll
      for (int ni = 0; ni < 4; ++ni) {
        float p = __expf(s[mi][ni][r] - mx);
        s[mi][ni][r] = p;
        sum += p;
      }
      sum += __shfl_xor(sum, 1);
      sum += __shfl_xor(sum, 2);
      sum += __shfl_xor(sum, 4);
      sum += __shfl_xor(sum, 8);
      float inv = __builtin_amdgcn_rcpf(sum);
#pragma unroll
      for (int ni = 0; ni < 4; ++ni) s[mi][ni][r] *= inv;
    }

  // ---- P -> LDS as bf16 (swizzled) ----
  u16* pl = P_lds[wid];
#pragma unroll
  for (int mi = 0; mi < 4; ++mi)
#pragma unroll
    for (int ni = 0; ni < 4; ++ni) {
      int col = ni * 16 + c;
#pragma unroll
      for (int r = 0; r < 4; ++r) {
        int row = mi * 16 + g * 4 + r;
        int byte = (row * 128 + col * 2) ^ ((row & 7) << 4);
        *(u16*)((char*)pl + byte) = f2b(s[mi][ni][r]);
      }
    }
  asm volatile("s_waitcnt lgkmcnt(0)" ::: "memory");  // wave's LDS writes visible

  // ---- O = P @ V ----
  f32x4 o[4][2] = {};
#pragma unroll
  for (int ks = 0; ks < 2; ++ks) {
    bf16x8 vb[2];
#pragma unroll
    for (int n2 = 0; n2 < 2; ++n2) {
      int d = n2 * 16 + c;
      int byte = (d * 128 + ks * 64 + g * 16) ^ ((d & 7) << 4);
      vb[n2] = __builtin_bit_cast(bf16x8, *(const u16x8*)((const char*)vt + byte));
    }
#pragma unroll
    for (int mi = 0; mi < 4; ++mi) {
      int row = mi * 16 + c;
      int byte = (row * 128 + ks * 64 + g * 16) ^ ((row & 7) << 4);
      bf16x8 pa = __builtin_bit_cast(bf16x8, *(const u16x8*)((const char*)pl + byte));
#pragma unroll
      for (int n2 = 0; n2 < 2; ++n2)
        o[mi][n2] = __builtin_amdgcn_mfma_f32_16x16x32_bf16(pa, vb[n2],
                                                            o[mi][n2], 0, 0, 0);
    }
  }

  // ---- store O[b, row, h*32 + d] as bf16 ----
  u16* obase = attnout + (size_t)b * (NTOK * DIM) + h * HD;
#pragma unroll
  for (int mi = 0; mi < 4; ++mi)
#pragma unroll
    for (int r = 0; r < 4; ++r) {
      int row = mi * 16 + g * 4 + r;
      if (row < NTOK) {
#pragma unroll
        for (int n2 = 0; n2 < 2; ++n2)
          obase[(size_t)row * DIM + n2 * 16 + c] = f2b(o[mi][n2][r]);
      }
    }
}

// ---------------------------------------------------------------------------
extern "C" void kernel_launch(void* const* d_in, const int* in_sizes, int n_in,
                              void* d_out, int out_size, void* d_ws, size_t ws_size,
                              hipStream_t stream) {
  const float* x       = (const float*)d_in[0];
  const float* qkv_w   = (const float*)d_in[1];
  const float* qkv_b   = (const float*)d_in[2];
  const float* proj_w  = (const float*)d_in[3];
  const float* proj_b  = (const float*)d_in[4];
  const float* bias_tb = (const float*)d_in[5];
  const float* mask    = (const float*)d_in[6];
  const int*   rel_idx = (const int*)d_in[7];
  float* out = (float*)d_out;

  char* ws = (char*)d_ws;
  u16*   xb      = (u16*)(ws + 0);                  //  77,070,336  x bf16
  u16*   wqkvb   = (u16*)(ws + 77070336);           //     884,736  qkv_w bf16
  u16*   wprojb  = (u16*)(ws + 77955072);           //     294,912  proj_w bf16
  float* rpbm    = (float*)(ws + 78249984);         //  12,582,912  bias+mask
  u16*   qkv     = (u16*)(ws + 90832896);           // 231,211,008  qkv bf16
  u16*   attnout = (u16*)(ws + 322043904);          //  77,070,336  attn out bf16
  // total = 399,114,240 bytes

  // 1) prep: all casts + fused bias+mask table
  k_prep<<<50496, 256, 0, stream>>>(x, xb, qkv_w, wqkvb, proj_w, wprojb,
                                    bias_tb, mask, rel_idx, rpbm);

  // 2) QKV GEMM: [100352,384] x [1152,384]^T -> bf16 [100352,1152]
  k_gemm<1, 1152, 9, 882><<<7056, 256, 0, stream>>>(xb, wqkvb, qkv_b, (void*)qkv);

  // 3) window attention -> bf16 [100352,384]
  k_attn<<<6144, 256, 0, stream>>>(qkv, rpbm, attnout);

  // 4) proj GEMM: [100352,384] x [384,384]^T + bias -> f32 d_out
  k_gemm<0, 384, 3, 294><<<2352, 256, 0, stream>>>(attnout, wprojb, proj_b,
                                                   (void*)out);

  (void)in_sizes; (void)n_in; (void)out_size; (void)ws_size;
}